// Round 15
// baseline (192.971 us; speedup 1.0000x reference)
//
#include <hip/hip_runtime.h>
#include <stdint.h>

#define EPS 1e-6f

constexpr int D    = 128;   // head_dim
constexpr int SEQ  = 4096;  // seq_len
constexpr int NBH  = 64;    // bsz*num_heads
constexpr int QT   = 64;    // q rows per block (pass 2)
constexpr int QCB  = 8;     // phiQ-conversion blocks per bh (fused into pass-1 grid)

typedef __attribute__((ext_vector_type(8)))  __bf16 bf16x8;
typedef __attribute__((ext_vector_type(4)))  __bf16 bf16x4;
typedef __attribute__((ext_vector_type(4)))  float  f32x4;
typedef __attribute__((ext_vector_type(16))) float  f32x16;

__device__ __forceinline__ float phi1(float x) {
    // elu(x)+1 : x>0 -> x+1 ; x<=0 -> exp(x). Branchless.
    return fmaxf(x, 0.0f) + __expf(fminf(x, 0.0f));
}

// ---------------- Pass 1 (fused): blocks split<P compute KVTp partials (MFMA,
// wave-autonomous, no LDS — R13 structure); blocks split>=P stream-convert
// phi(Q)->bf16 into Qb, soaking the ~4 TB/s of HBM bandwidth the latency-bound
// MFMA blocks leave idle (9 schedule variants pinned their read rate at 1.2-1.4 TB/s
// with all pipes <35% busy — so overlap independent streaming work instead).
__global__ __launch_bounds__(512, 4) void kv_partial_mfma(const float* __restrict__ K,
                                                          const float* __restrict__ V,
                                                          const float* __restrict__ Qf,
                                                          __bf16* __restrict__ Qb,
                                                          float* __restrict__ KVTp,
                                                          float* __restrict__ Zp,
                                                          int chunk, int P) {
    const int split = blockIdx.x, bh = blockIdx.y;
    const int tid  = threadIdx.x;

    if (split >= P) {
        // ---- phiQ conversion block: rows [qs*512, qs*512+512) of Q[bh] -> bf16 phi(Q)
        const int qs = split - P;
        const size_t qbase = (size_t)bh * SEQ * D + (size_t)qs * (SEQ / QCB) * D;
        const float* qsrc = Qf + qbase;
        __bf16* qdst = Qb + qbase;
        // 512 rows x 128 cols = 16384 float4 chunks; 512 threads x 32 iters
#pragma unroll 4
        for (int it = 0; it < 32; ++it) {
            const int f4 = it * 512 + tid;
            const float4 qv = *(const float4*)(qsrc + (size_t)f4 * 4);
            bf16x4 qb4;
            qb4[0] = (__bf16)phi1(qv.x); qb4[1] = (__bf16)phi1(qv.y);
            qb4[2] = (__bf16)phi1(qv.z); qb4[3] = (__bf16)phi1(qv.w);
            *(bf16x4*)(qdst + (size_t)f4 * 4) = qb4;
        }
        return;
    }

    // ---- MFMA partial block (R13 wave-autonomous structure)
    const int lane = tid & 63;
    const int wave = tid >> 6;
    const int k0   = split * chunk;
    const size_t base = (size_t)bh * SEQ * D;

    const int we  = wave >> 2;                       // 0..1
    const int wd  = wave & 3;                        // 0..3
    const int er0 = we * 64 + (lane & 31);           // A row (e), strip 0
    const int er1 = er0 + 32;                        // A row (e), strip 1
    const int dr  = wd * 32 + (lane & 31);           // B col (d)
    const int kh  = (lane >> 5) * 8;                 // k-half of the 16-k step

    f32x16 acc0, acc1;
#pragma unroll
    for (int i = 0; i < 16; ++i) { acc0[i] = 0.f; acc1[i] = 0.f; }
    float zacc = 0.f;
    const bool doZ = (we == 0);

    const int tiles = chunk / 16;

    float av0[8], av1[8], ak[8];    // prefetch set A (tile t)
    float bv0[8], bv1[8], bk_[8];   // prefetch set B (tile t+1)

#define P1_LOAD(V0, V1, KK, T) { \
        const size_t kb = base + (size_t)(k0 + (T) * 16 + kh) * D; \
        _Pragma("unroll") \
        for (int i = 0; i < 8; ++i) { \
            V0[i] = V[kb + (size_t)i * D + er0]; \
            V1[i] = V[kb + (size_t)i * D + er1]; \
            KK[i] = K[kb + (size_t)i * D + dr]; \
        } }

#define P1_CONSUME(V0, V1, KK) { \
        bf16x8 fa0, fa1, fb; \
        _Pragma("unroll") \
        for (int i = 0; i < 8; ++i) { \
            const float p = phi1(KK[i]); \
            fa0[i] = (__bf16)V0[i]; \
            fa1[i] = (__bf16)V1[i]; \
            fb[i]  = (__bf16)p; \
            if (doZ) zacc += p; \
        } \
        acc0 = __builtin_amdgcn_mfma_f32_32x32x16_bf16(fa0, fb, acc0, 0, 0, 0); \
        acc1 = __builtin_amdgcn_mfma_f32_32x32x16_bf16(fa1, fb, acc1, 0, 0, 0); }

    P1_LOAD(av0, av1, ak, 0)

    for (int t = 0; t < tiles; t += 2) {
        if (t + 1 < tiles) P1_LOAD(bv0, bv1, bk_, t + 1)
        P1_CONSUME(av0, av1, ak)
        if (t + 2 < tiles) P1_LOAD(av0, av1, ak, t + 2)
        P1_CONSUME(bv0, bv1, bk_)
    }
#undef P1_LOAD
#undef P1_CONSUME

    // store C partials (f32). C/D: col = lane&31, row = (reg&3) + 8*(reg>>2) + 4*(lane>>5)
    float* kvb = KVTp + ((size_t)split * NBH + bh) * D * D;
    const int ebase = we * 64 + 4 * (lane >> 5);
    const int dcol  = wd * 32 + (lane & 31);
#pragma unroll
    for (int r = 0; r < 16; ++r) {
        const int e = ebase + (r & 3) + 8 * (r >> 2);
        kvb[(size_t)e * D + dcol]        = acc0[r];
        kvb[(size_t)(e + 32) * D + dcol] = acc1[r];
    }

    if (doZ) {
        zacc += __shfl_xor(zacc, 32);
        if (lane < 32) {
            Zp[((size_t)split * NBH + bh) * D + wd * 32 + lane] = zacc;
        }
    }
}

// ---------------- Reduce partials -> bf16: KVT[bh][e][d], Zb[bh][d]
__global__ __launch_bounds__(256) void reduce_bf16_kernel(const float* __restrict__ KVTp,
                                                          const float* __restrict__ Zp,
                                                          __bf16* __restrict__ KVT,
                                                          __bf16* __restrict__ Zb,
                                                          int P) {
    constexpr int KVF8 = NBH * D * D / 8;  // 131072
    constexpr int ZF8  = NBH * D / 8;      // 1024
    const int idx = blockIdx.x * 256 + threadIdx.x;
    if (idx < KVF8) {
        const size_t b0 = (size_t)idx * 8;
        float4 s0 = *(const float4*)(KVTp + b0);
        float4 s1 = *(const float4*)(KVTp + b0 + 4);
        for (int s = 1; s < P; ++s) {
            const float* p = KVTp + (size_t)s * NBH * D * D + b0;
            const float4 a = *(const float4*)(p);
            const float4 b = *(const float4*)(p + 4);
            s0.x += a.x; s0.y += a.y; s0.z += a.z; s0.w += a.w;
            s1.x += b.x; s1.y += b.y; s1.z += b.z; s1.w += b.w;
        }
        bf16x8 o;
        o[0] = (__bf16)s0.x; o[1] = (__bf16)s0.y; o[2] = (__bf16)s0.z; o[3] = (__bf16)s0.w;
        o[4] = (__bf16)s1.x; o[5] = (__bf16)s1.y; o[6] = (__bf16)s1.z; o[7] = (__bf16)s1.w;
        *(bf16x8*)(KVT + b0) = o;
    } else if (idx < KVF8 + ZF8) {
        const size_t b0 = (size_t)(idx - KVF8) * 8;
        float4 s0 = *(const float4*)(Zp + b0);
        float4 s1 = *(const float4*)(Zp + b0 + 4);
        for (int s = 1; s < P; ++s) {
            const float* p = Zp + (size_t)s * NBH * D + b0;
            const float4 a = *(const float4*)(p);
            const float4 b = *(const float4*)(p + 4);
            s0.x += a.x; s0.y += a.y; s0.z += a.z; s0.w += a.w;
            s1.x += b.x; s1.y += b.y; s1.z += b.z; s1.w += b.w;
        }
        bf16x8 o;
        o[0] = (__bf16)s0.x; o[1] = (__bf16)s0.y; o[2] = (__bf16)s0.z; o[3] = (__bf16)s0.w;
        o[4] = (__bf16)s1.x; o[5] = (__bf16)s1.y; o[6] = (__bf16)s1.z; o[7] = (__bf16)s1.w;
        *(bf16x8*)(Zb + b0) = o;
    }
}

// ---------------- Pass 2 (MFMA): out[q][e] = (phiQ[q][:] @ KV) / (phiQ[q][:] . Z + EPS)
// Dual Q path: bf16 phi(Q) from Qb (preconverted during pass 1) or f32 fallback.
__global__ __launch_bounds__(256, 3) void attn_out_mfma(const float* __restrict__ Qf,
                                                        const __bf16* __restrict__ Qb,
                                                        const __bf16* __restrict__ KVT,
                                                        const __bf16* __restrict__ Zb,
                                                        float* __restrict__ out,
                                                        int useQb) {
    __shared__ __bf16 sKVT[D][D];   // 32 KB, row-XOR-swizzled
    __shared__ __bf16 sQ[QT][D];    // 16 KB, row-XOR-swizzled
    __shared__ __bf16 sZ[D];        // 256 B, linear

    const int bh  = blockIdx.x;
    const int q0  = blockIdx.y * QT;
    const int tid = threadIdx.x;
    const int lane = tid & 63;
    const int wave = tid >> 6;
    const size_t base = (size_t)bh * SEQ * D;

    // stage KVT (bf16 global, swizzle: 8-elem seg ^ (row&7))
    {
        const __bf16* kvg = KVT + (size_t)bh * D * D;
#pragma unroll
        for (int j = 0; j < 8; ++j) {
            const int f   = tid + 256 * j;
            const int e   = f >> 4;
            const int seg = f & 15;
            const bf16x8 v = *(const bf16x8*)(kvg + (size_t)f * 8);
            *(bf16x8*)(&sKVT[e][(seg ^ (e & 7)) * 8]) = v;
        }
    }
    if (tid < 16) {
        *(bf16x8*)(&sZ[tid * 8]) = *(const bf16x8*)(Zb + bh * D + tid * 8);
    }
    // stage phi(Q) as bf16, swizzled — from Qb (fast path) or f32 Q (fallback)
    if (useQb) {
        const __bf16* qg = Qb + base + (size_t)q0 * D;
#pragma unroll
        for (int j = 0; j < 4; ++j) {
            const int f   = tid + 256 * j;   // 1024 chunks of 8 bf16 (64 rows x 16)
            const int r   = f >> 4;
            const int seg = f & 15;
            const bf16x8 v = *(const bf16x8*)(qg + (size_t)f * 8);
            *(bf16x8*)(&sQ[r][(seg ^ (r & 7)) * 8]) = v;
        }
    } else {
#pragma unroll
        for (int j = 0; j < 8; ++j) {
            const int f  = tid + 256 * j;
            const int r  = f >> 5;
            const int c4 = (f & 31) * 4;
            const float4 qv = *(const float4*)(Qf + base + (size_t)(q0 + r) * D + c4);
            bf16x4 qb;
            qb[0] = (__bf16)phi1(qv.x); qb[1] = (__bf16)phi1(qv.y);
            qb[2] = (__bf16)phi1(qv.z); qb[3] = (__bf16)phi1(qv.w);
            *(bf16x4*)(&sQ[r][c4 ^ ((r & 7) * 8)]) = qb;
        }
    }
    __syncthreads();

    f32x4 acc[8];
#pragma unroll
    for (int et = 0; et < 8; ++et) acc[et] = (f32x4){0.f, 0.f, 0.f, 0.f};
    f32x4 accz = (f32x4){0.f, 0.f, 0.f, 0.f};

    const int qw   = wave * 16;
    const int lrow = lane & 15;
    const int lq   = lane >> 4;

#pragma unroll
    for (int dblk = 0; dblk < 4; ++dblk) {
        const int dbase = dblk * 32 + lq * 8;
        const int arow  = qw + lrow;
        const bf16x8 af = *(const bf16x8*)(&sQ[arow][dbase ^ ((arow & 7) * 8)]);
        const bf16x8 zf = *(const bf16x8*)(&sZ[dbase]);
        accz = __builtin_amdgcn_mfma_f32_16x16x32_bf16(af, zf, accz, 0, 0, 0);
#pragma unroll
        for (int et = 0; et < 8; ++et) {
            const int brow = et * 16 + lrow;
            const bf16x8 bfr = *(const bf16x8*)(&sKVT[brow][dbase ^ ((brow & 7) * 8)]);
            acc[et] = __builtin_amdgcn_mfma_f32_16x16x32_bf16(af, bfr, acc[et], 0, 0, 0);
        }
    }

    // epilogue: C/D layout col=lane&15, row=(lane>>4)*4+reg
    float inv[4];
#pragma unroll
    for (int r = 0; r < 4; ++r) inv[r] = 1.0f / (accz[r] + EPS);
    float* ob = out + base + (size_t)(q0 + qw + lq * 4) * D + lrow;
#pragma unroll
    for (int r = 0; r < 4; ++r) {
#pragma unroll
        for (int et = 0; et < 8; ++et) {
            ob[(size_t)r * D + et * 16] = acc[et][r] * inv[r];
        }
    }
}

extern "C" void kernel_launch(void* const* d_in, const int* in_sizes, int n_in,
                              void* d_out, int out_size, void* d_ws, size_t ws_size,
                              hipStream_t stream) {
    const float* Q = (const float*)d_in[0];
    const float* K = (const float*)d_in[1];
    const float* V = (const float*)d_in[2];
    float* out = (float*)d_out;

    // ws layout: [Qb: NBH*SEQ*D bf16 (optional)][KVTp: P*NBH*D*D f32][Zp: P*NBH*D f32]
    //            [KVT: NBH*D*D bf16][Zb: NBH*D bf16]
    const size_t per_split_f = (size_t)NBH * D * D + (size_t)NBH * D;
    const size_t tail_bytes  = ((size_t)NBH * D * D + (size_t)NBH * D) * sizeof(__bf16);
    const size_t qb_bytes    = (size_t)NBH * SEQ * D * sizeof(__bf16);   // 64 MB

    int P = 8;
    int useQb = 1;
    if (qb_bytes + (size_t)P * per_split_f * sizeof(float) + tail_bytes > ws_size) {
        useQb = 0;
        P = 16;
        while (P > 1 && (size_t)P * per_split_f * sizeof(float) + tail_bytes > ws_size) P >>= 1;
    }
    const int chunk = SEQ / P;

    char* wp = (char*)d_ws;
    __bf16* Qb = nullptr;
    if (useQb) { Qb = (__bf16*)wp; wp += qb_bytes; }
    float*  KVTp = (float*)wp;
    float*  Zp   = KVTp + (size_t)P * NBH * D * D;
    __bf16* KVT  = (__bf16*)(Zp + (size_t)P * NBH * D);
    __bf16* Zb   = KVT + (size_t)NBH * D * D;

    const int gx = P + (useQb ? QCB : 0);
    kv_partial_mfma<<<dim3(gx, NBH), 512, 0, stream>>>(K, V, Q, Qb, KVTp, Zp, chunk, P);

    constexpr int RED_ITEMS = NBH * D * D / 8 + NBH * D / 8;
    reduce_bf16_kernel<<<(RED_ITEMS + 255) / 256, 256, 0, stream>>>(KVTp, Zp, KVT, Zb, P);

    attn_out_mfma<<<dim3(NBH, SEQ / QT), 256, 0, stream>>>(Q, Qb, KVT, Zb, out, useQb);
}

// Round 16
// 178.329 us; speedup vs baseline: 1.0821x; 1.0821x over previous
//
#include <hip/hip_runtime.h>
#include <stdint.h>

#define EPS 1e-6f

constexpr int D    = 128;   // head_dim
constexpr int SEQ  = 4096;  // seq_len
constexpr int NBH  = 64;    // bsz*num_heads
constexpr int QT   = 64;    // q rows per block (pass 2)

typedef __attribute__((ext_vector_type(8)))  __bf16 bf16x8;
typedef __attribute__((ext_vector_type(4)))  __bf16 bf16x4;
typedef __attribute__((ext_vector_type(4)))  float  f32x4;
typedef __attribute__((ext_vector_type(16))) float  f32x16;

__device__ __forceinline__ float phi1(float x) {
    // elu(x)+1 : x>0 -> x+1 ; x<=0 -> exp(x). Branchless.
    return fmaxf(x, 0.0f) + __expf(fminf(x, 0.0f));
}

// ---------------- Pass 1 (MFMA, wave-autonomous, NO LDS / NO barriers):
// KVTp[split][bh][e][d] = sum_k V[k][e]*phiK[k][d]  (f32 partials)
// Column fragment reads are line-coalesced (lanes 0-31 = one 128B line, lanes 32-63 the
// k+8 line). 10 schedule variants (R5-R15) pinned this op family's read rate at
// ~1.2-1.4 TB/s — structure kept at its best-known form; P=4 -> grid 256 = 1 block/CU
// (halves HBM stream count, cuts partial traffic 4x).
__global__ __launch_bounds__(512, 4) void kv_partial_mfma(const float* __restrict__ K,
                                                          const float* __restrict__ V,
                                                          float* __restrict__ KVTp,
                                                          float* __restrict__ Zp,
                                                          int chunk) {
    const int split = blockIdx.x, bh = blockIdx.y;
    const int tid  = threadIdx.x;
    const int lane = tid & 63;
    const int wave = tid >> 6;
    const int k0   = split * chunk;
    const size_t base = (size_t)bh * SEQ * D;

    // wave grid: 2e x 4d -> each wave owns a 64e x 32d strip
    const int we  = wave >> 2;                       // 0..1
    const int wd  = wave & 3;                        // 0..3
    const int er0 = we * 64 + (lane & 31);           // A row (e), strip 0
    const int er1 = er0 + 32;                        // A row (e), strip 1
    const int dr  = wd * 32 + (lane & 31);           // B col (d)
    const int kh  = (lane >> 5) * 8;                 // k-half of the 16-k step

    f32x16 acc0, acc1;
#pragma unroll
    for (int i = 0; i < 16; ++i) { acc0[i] = 0.f; acc1[i] = 0.f; }
    float zacc = 0.f;
    const bool doZ = (we == 0);   // waves 0-3 own Z for their d-strip (no overlap)

    const int tiles = chunk / 16;   // even for all P in {1,2,4,8,16}

    float av0[8], av1[8], ak[8];    // prefetch set A (tile t)
    float bv0[8], bv1[8], bk_[8];   // prefetch set B (tile t+1)

#define P1_LOAD(V0, V1, KK, T) { \
        const size_t kb = base + (size_t)(k0 + (T) * 16 + kh) * D; \
        _Pragma("unroll") \
        for (int i = 0; i < 8; ++i) { \
            V0[i] = V[kb + (size_t)i * D + er0]; \
            V1[i] = V[kb + (size_t)i * D + er1]; \
            KK[i] = K[kb + (size_t)i * D + dr]; \
        } }

#define P1_CONSUME(V0, V1, KK) { \
        bf16x8 fa0, fa1, fb; \
        _Pragma("unroll") \
        for (int i = 0; i < 8; ++i) { \
            const float p = phi1(KK[i]); \
            fa0[i] = (__bf16)V0[i]; \
            fa1[i] = (__bf16)V1[i]; \
            fb[i]  = (__bf16)p; \
            if (doZ) zacc += p; \
        } \
        acc0 = __builtin_amdgcn_mfma_f32_32x32x16_bf16(fa0, fb, acc0, 0, 0, 0); \
        acc1 = __builtin_amdgcn_mfma_f32_32x32x16_bf16(fa1, fb, acc1, 0, 0, 0); }

    P1_LOAD(av0, av1, ak, 0)

    for (int t = 0; t < tiles; t += 2) {
        if (t + 1 < tiles) P1_LOAD(bv0, bv1, bk_, t + 1)
        P1_CONSUME(av0, av1, ak)
        if (t + 2 < tiles) P1_LOAD(av0, av1, ak, t + 2)
        P1_CONSUME(bv0, bv1, bk_)
    }
#undef P1_LOAD
#undef P1_CONSUME

    // store C partials (f32). C/D: col = lane&31, row = (reg&3) + 8*(reg>>2) + 4*(lane>>5)
    float* kvb = KVTp + ((size_t)split * NBH + bh) * D * D;
    const int ebase = we * 64 + 4 * (lane >> 5);
    const int dcol  = wd * 32 + (lane & 31);
#pragma unroll
    for (int r = 0; r < 16; ++r) {
        const int e = ebase + (r & 3) + 8 * (r >> 2);
        kvb[(size_t)e * D + dcol]        = acc0[r];
        kvb[(size_t)(e + 32) * D + dcol] = acc1[r];
    }

    // Z: lane l covers k-half kh at d = dr; lane l^32 covers the other k-half
    if (doZ) {
        zacc += __shfl_xor(zacc, 32);
        if (lane < 32) {
            Zp[((size_t)split * NBH + bh) * D + wd * 32 + lane] = zacc;
        }
    }
}

// ---------------- Pass 2 (MFMA, fused partial-reduce):
// out[q][e] = (phiQ[q][:] @ KV) / (phiQ[q][:] . Z + EPS)
// Stages KVT by summing the P f32 partials inline (17 MB partials are L3-resident, so
// the 64x re-read per bh is L3-served) — the separate reduce kernel is eliminated.
__global__ __launch_bounds__(256, 3) void attn_out_mfma(const float* __restrict__ Q,
                                                        const float* __restrict__ KVTp,
                                                        const float* __restrict__ Zp,
                                                        float* __restrict__ out,
                                                        int P) {
    __shared__ __bf16 sKVT[D][D];   // 32 KB, row-XOR-swizzled
    __shared__ __bf16 sQ[QT][D];    // 16 KB, row-XOR-swizzled
    __shared__ __bf16 sZ[D];        // 256 B, linear

    const int bh  = blockIdx.x;
    const int q0  = blockIdx.y * QT;
    const int tid = threadIdx.x;
    const int lane = tid & 63;
    const int wave = tid >> 6;
    const size_t base = (size_t)bh * SEQ * D;

    // stage KVT: sum P f32 partials -> bf16, swizzle (8-elem seg ^ (row&7))
    {
        const float* kvp = KVTp + (size_t)bh * D * D;
        const size_t pstride = (size_t)NBH * D * D;
#pragma unroll
        for (int j = 0; j < 8; ++j) {
            const int f = tid + 256 * j;           // 2048 chunks of 8 f32
            const size_t b0 = (size_t)f * 8;
            float4 s0 = *(const float4*)(kvp + b0);
            float4 s1 = *(const float4*)(kvp + b0 + 4);
            for (int s = 1; s < P; ++s) {
                const float* p = kvp + (size_t)s * pstride + b0;
                const float4 a = *(const float4*)(p);
                const float4 b = *(const float4*)(p + 4);
                s0.x += a.x; s0.y += a.y; s0.z += a.z; s0.w += a.w;
                s1.x += b.x; s1.y += b.y; s1.z += b.z; s1.w += b.w;
            }
            bf16x8 o;
            o[0] = (__bf16)s0.x; o[1] = (__bf16)s0.y; o[2] = (__bf16)s0.z; o[3] = (__bf16)s0.w;
            o[4] = (__bf16)s1.x; o[5] = (__bf16)s1.y; o[6] = (__bf16)s1.z; o[7] = (__bf16)s1.w;
            const int e   = f >> 4;
            const int seg = f & 15;
            *(bf16x8*)(&sKVT[e][(seg ^ (e & 7)) * 8]) = o;
        }
    }
    // stage Z: sum P f32 partials -> bf16
    if (tid < 16) {
        const float* zp = Zp + (size_t)bh * D + tid * 8;
        const size_t zstride = (size_t)NBH * D;
        float4 s0 = *(const float4*)(zp);
        float4 s1 = *(const float4*)(zp + 4);
        for (int s = 1; s < P; ++s) {
            const float* p = zp + (size_t)s * zstride;
            const float4 a = *(const float4*)(p);
            const float4 b = *(const float4*)(p + 4);
            s0.x += a.x; s0.y += a.y; s0.z += a.z; s0.w += a.w;
            s1.x += b.x; s1.y += b.y; s1.z += b.z; s1.w += b.w;
        }
        bf16x8 o;
        o[0] = (__bf16)s0.x; o[1] = (__bf16)s0.y; o[2] = (__bf16)s0.z; o[3] = (__bf16)s0.w;
        o[4] = (__bf16)s1.x; o[5] = (__bf16)s1.y; o[6] = (__bf16)s1.z; o[7] = (__bf16)s1.w;
        *(bf16x8*)(&sZ[tid * 8]) = o;
    }
    // stage phi(Q) as bf16, swizzled
    {
#pragma unroll
        for (int j = 0; j < 8; ++j) {
            const int f  = tid + 256 * j;
            const int r  = f >> 5;
            const int c4 = (f & 31) * 4;
            const float4 qv = *(const float4*)(Q + base + (size_t)(q0 + r) * D + c4);
            bf16x4 qb;
            qb[0] = (__bf16)phi1(qv.x); qb[1] = (__bf16)phi1(qv.y);
            qb[2] = (__bf16)phi1(qv.z); qb[3] = (__bf16)phi1(qv.w);
            *(bf16x4*)(&sQ[r][c4 ^ ((r & 7) * 8)]) = qb;
        }
    }
    __syncthreads();

    f32x4 acc[8];
#pragma unroll
    for (int et = 0; et < 8; ++et) acc[et] = (f32x4){0.f, 0.f, 0.f, 0.f};
    f32x4 accz = (f32x4){0.f, 0.f, 0.f, 0.f};

    const int qw   = wave * 16;
    const int lrow = lane & 15;
    const int lq   = lane >> 4;

#pragma unroll
    for (int dblk = 0; dblk < 4; ++dblk) {
        const int dbase = dblk * 32 + lq * 8;
        const int arow  = qw + lrow;
        const bf16x8 af = *(const bf16x8*)(&sQ[arow][dbase ^ ((arow & 7) * 8)]);
        const bf16x8 zf = *(const bf16x8*)(&sZ[dbase]);
        accz = __builtin_amdgcn_mfma_f32_16x16x32_bf16(af, zf, accz, 0, 0, 0);
#pragma unroll
        for (int et = 0; et < 8; ++et) {
            const int brow = et * 16 + lrow;
            const bf16x8 bfr = *(const bf16x8*)(&sKVT[brow][dbase ^ ((brow & 7) * 8)]);
            acc[et] = __builtin_amdgcn_mfma_f32_16x16x32_bf16(af, bfr, acc[et], 0, 0, 0);
        }
    }

    // epilogue: C/D layout col=lane&15, row=(lane>>4)*4+reg
    float inv[4];
#pragma unroll
    for (int r = 0; r < 4; ++r) inv[r] = 1.0f / (accz[r] + EPS);
    float* ob = out + base + (size_t)(q0 + qw + lq * 4) * D + lrow;
#pragma unroll
    for (int r = 0; r < 4; ++r) {
#pragma unroll
        for (int et = 0; et < 8; ++et) {
            ob[(size_t)r * D + et * 16] = acc[et][r] * inv[r];
        }
    }
}

extern "C" void kernel_launch(void* const* d_in, const int* in_sizes, int n_in,
                              void* d_out, int out_size, void* d_ws, size_t ws_size,
                              hipStream_t stream) {
    const float* Q = (const float*)d_in[0];
    const float* K = (const float*)d_in[1];
    const float* V = (const float*)d_in[2];
    float* out = (float*)d_out;

    // ws layout: [KVTp: P*NBH*D*D f32][Zp: P*NBH*D f32]
    const size_t per_split_f = (size_t)NBH * D * D + (size_t)NBH * D;
    int P = 4;
    while (P > 1 && (size_t)P * per_split_f * sizeof(float) > ws_size) P >>= 1;
    const int chunk = SEQ / P;   // 1024 at P=4; chunk/16 even for all fallbacks

    float* KVTp = (float*)d_ws;
    float* Zp   = KVTp + (size_t)P * NBH * D * D;

    kv_partial_mfma<<<dim3(P, NBH), 512, 0, stream>>>(K, V, KVTp, Zp, chunk);
    attn_out_mfma<<<dim3(NBH, SEQ / QT), 256, 0, stream>>>(Q, KVTp, Zp, out, P);
}

// Round 17
// 135.201 us; speedup vs baseline: 1.4273x; 1.3190x over previous
//
#include <hip/hip_runtime.h>
#include <stdint.h>

#define EPS 1e-6f

constexpr int D    = 128;   // head_dim
constexpr int SEQ  = 4096;  // seq_len
constexpr int NBH  = 64;    // bsz*num_heads
constexpr int TK   = 16;    // k rows per LDS tile (pass 1)
constexpr int QT   = 64;    // q rows per block (pass 2)

typedef __attribute__((ext_vector_type(8)))  __bf16 bf16x8;
typedef __attribute__((ext_vector_type(4)))  __bf16 bf16x4;
typedef __attribute__((ext_vector_type(4)))  float  f32x4;
typedef __attribute__((ext_vector_type(16))) float  f32x16;

typedef const __attribute__((address_space(1))) uint32_t* as1_u32p;
typedef __attribute__((address_space(3))) uint32_t*       as3_u32p;

__device__ __forceinline__ float phi1(float x) {
    // elu(x)+1 : x>0 -> x+1 ; x<=0 -> exp(x). Branchless.
    return fmaxf(x, 0.0f) + __expf(fminf(x, 0.0f));
}

// ---------------- Pass 1 (MFMA + global_load_lds, depth-3 pipeline) — best-measured
// family member (R12, 147 µs total). KVTp[split][bh][e][d] = sum_k V[k][e]*phiK[k][d].
// 4 LDS buffers; loads for tile t+3 issued at tile t; steady-state vmcnt(6). Wave map
// 2e x 4d (phi redundancy 2x). NOTE: pass-1 duration (~108 µs) was invariant across 11
// structural variants (R5-R16: staging style/width/depth/barriers/LDS/occupancy/block
// count) — latency-bound with all pipes <30%; this is the best-known form.
__global__ __launch_bounds__(512, 4) void kv_partial_mfma(const float* __restrict__ K,
                                                          const float* __restrict__ V,
                                                          float* __restrict__ KVTp,
                                                          float* __restrict__ Zp,
                                                          int chunk) {
    __shared__ float stile[4][2][TK][D];   // [buf][K|V][k][col] = 64 KB -> 2 blocks/CU

    const int split = blockIdx.x, bh = blockIdx.y;
    const int tid  = threadIdx.x;
    const int lane = tid & 63;
    const int wave = tid >> 6;
    const int k0   = split * chunk;
    const size_t base = (size_t)bh * SEQ * D;

    // staging role: waves 0-3 issue K tile, waves 4-7 issue V tile; 2 x 16B per thread
    const int  mat = wave >> 2;             // 0 = K, 1 = V
    const int  w4  = wave & 3;
    const float* __restrict__ src = mat ? V : K;
    const int eoff0 = (w4 * 2 + 0) * 256 + lane * 4;  // float offset within [16][128] tile
    const int eoff1 = (w4 * 2 + 1) * 256 + lane * 4;

    // compute role: 2e x 4d wave grid
    const int we = wave >> 2;                        // 0..1 -> e-base we*64
    const int wd = wave & 3;                         // 0..3 -> d-strip wd*32
    const int er0 = we * 64 + (lane & 31);           // A row (e), strip 0
    const int er1 = er0 + 32;                        // A row (e), strip 1
    const int dr  = wd * 32 + (lane & 31);           // B col (d)
    const int kh  = (lane >> 5) * 8;                 // k-half of the 16-k step

    f32x16 acc0, acc1;
#pragma unroll
    for (int i = 0; i < 16; ++i) { acc0[i] = 0.f; acc1[i] = 0.f; }
    float zacc = 0.f;
    const bool doZ = (we == 0);   // waves 0-3 own Z for their own d-strip

    const int tiles = chunk / TK;

#define ISSUE(BUF, T) { \
        const float* g = src + base + (size_t)(k0 + (T) * TK) * D; \
        float* l = &stile[BUF][mat][0][0]; \
        __builtin_amdgcn_global_load_lds((as1_u32p)(const void*)(g + eoff0), \
                                         (as3_u32p)(void*)(l + eoff0), 16, 0, 0); \
        __builtin_amdgcn_global_load_lds((as1_u32p)(const void*)(g + eoff1), \
                                         (as3_u32p)(void*)(l + eoff1), 16, 0, 0); }

    // prologue: 3 tiles in flight (6 loads/wave)
    ISSUE(0, 0)
    ISSUE(1, 1)
    ISSUE(2, 2)

    for (int t = 0; t < tiles; ++t) {
        const int buf = t & 3;
        if (t + 3 < tiles) {
            ISSUE((t + 3) & 3, t + 3)
            asm volatile("s_waitcnt vmcnt(6)" ::: "memory");  // t's 2 done; 6 in flight
        } else if (t + 2 < tiles) {
            asm volatile("s_waitcnt vmcnt(4)" ::: "memory");
        } else if (t + 1 < tiles) {
            asm volatile("s_waitcnt vmcnt(2)" ::: "memory");
        } else {
            asm volatile("s_waitcnt vmcnt(0)" ::: "memory");
        }
        __builtin_amdgcn_s_barrier();        // all waves' tile-t writes visible
        __builtin_amdgcn_sched_barrier(0);

        const float* kt = &stile[buf][0][0][0];
        const float* vt = &stile[buf][1][0][0];

        bf16x8 av0, av1, bk;
#pragma unroll
        for (int i = 0; i < 8; ++i) {
            const float fv0 = vt[(kh + i) * D + er0];
            const float fv1 = vt[(kh + i) * D + er1];
            const float p   = phi1(kt[(kh + i) * D + dr]);
            av0[i] = (__bf16)fv0;
            av1[i] = (__bf16)fv1;
            bk[i]  = (__bf16)p;
            if (doZ) zacc += p;
        }
        acc0 = __builtin_amdgcn_mfma_f32_32x32x16_bf16(av0, bk, acc0, 0, 0, 0);
        acc1 = __builtin_amdgcn_mfma_f32_32x32x16_bf16(av1, bk, acc1, 0, 0, 0);

        asm volatile("s_waitcnt lgkmcnt(0)" ::: "memory");   // my ds_reads retired
        __builtin_amdgcn_s_barrier();                         // buf reusable at t+1's ISSUE
        __builtin_amdgcn_sched_barrier(0);
    }
#undef ISSUE

    // store C partials (f32). C/D: col = lane&31, row = (reg&3) + 8*(reg>>2) + 4*(lane>>5)
    float* kvb = KVTp + ((size_t)split * NBH + bh) * D * D;
    const int ebase = we * 64 + 4 * (lane >> 5);
    const int dcol  = wd * 32 + (lane & 31);
#pragma unroll
    for (int r = 0; r < 16; ++r) {
        const int e = ebase + (r & 3) + 8 * (r >> 2);
        kvb[(size_t)e * D + dcol]        = acc0[r];
        kvb[(size_t)(e + 32) * D + dcol] = acc1[r];
    }

    // Z: lane l covers k-half kh at d = dr; lane l^32 covers the other k-half
    if (doZ) {
        zacc += __shfl_xor(zacc, 32);
        if (lane < 32) {
            Zp[((size_t)split * NBH + bh) * D + wd * 32 + lane] = zacc;
        }
    }
}

// ---------------- Reduce partials -> bf16: KVT[bh][e][d], Zb[bh][d]
__global__ __launch_bounds__(256) void reduce_bf16_kernel(const float* __restrict__ KVTp,
                                                          const float* __restrict__ Zp,
                                                          __bf16* __restrict__ KVT,
                                                          __bf16* __restrict__ Zb,
                                                          int P) {
    constexpr int KVF8 = NBH * D * D / 8;  // 131072
    constexpr int ZF8  = NBH * D / 8;      // 1024
    const int idx = blockIdx.x * 256 + threadIdx.x;
    if (idx < KVF8) {
        const size_t b0 = (size_t)idx * 8;
        float4 s0 = *(const float4*)(KVTp + b0);
        float4 s1 = *(const float4*)(KVTp + b0 + 4);
        for (int s = 1; s < P; ++s) {
            const float* p = KVTp + (size_t)s * NBH * D * D + b0;
            const float4 a = *(const float4*)(p);
            const float4 b = *(const float4*)(p + 4);
            s0.x += a.x; s0.y += a.y; s0.z += a.z; s0.w += a.w;
            s1.x += b.x; s1.y += b.y; s1.z += b.z; s1.w += b.w;
        }
        bf16x8 o;
        o[0] = (__bf16)s0.x; o[1] = (__bf16)s0.y; o[2] = (__bf16)s0.z; o[3] = (__bf16)s0.w;
        o[4] = (__bf16)s1.x; o[5] = (__bf16)s1.y; o[6] = (__bf16)s1.z; o[7] = (__bf16)s1.w;
        *(bf16x8*)(KVT + b0) = o;
    } else if (idx < KVF8 + ZF8) {
        const size_t b0 = (size_t)(idx - KVF8) * 8;
        float4 s0 = *(const float4*)(Zp + b0);
        float4 s1 = *(const float4*)(Zp + b0 + 4);
        for (int s = 1; s < P; ++s) {
            const float* p = Zp + (size_t)s * NBH * D + b0;
            const float4 a = *(const float4*)(p);
            const float4 b = *(const float4*)(p + 4);
            s0.x += a.x; s0.y += a.y; s0.z += a.z; s0.w += a.w;
            s1.x += b.x; s1.y += b.y; s1.z += b.z; s1.w += b.w;
        }
        bf16x8 o;
        o[0] = (__bf16)s0.x; o[1] = (__bf16)s0.y; o[2] = (__bf16)s0.z; o[3] = (__bf16)s0.w;
        o[4] = (__bf16)s1.x; o[5] = (__bf16)s1.y; o[6] = (__bf16)s1.z; o[7] = (__bf16)s1.w;
        *(bf16x8*)(Zb + b0) = o;
    }
}

// ---------------- Pass 2 (MFMA): out[q][e] = (phiQ[q][:] @ KV) / (phiQ[q][:] . Z + EPS)
__global__ __launch_bounds__(256, 3) void attn_out_mfma(const float* __restrict__ Q,
                                                        const __bf16* __restrict__ KVT,
                                                        const __bf16* __restrict__ Zb,
                                                        float* __restrict__ out) {
    __shared__ __bf16 sKVT[D][D];   // 32 KB, row-XOR-swizzled
    __shared__ __bf16 sQ[QT][D];    // 16 KB, row-XOR-swizzled
    __shared__ __bf16 sZ[D];        // 256 B, linear

    const int bh  = blockIdx.x;
    const int q0  = blockIdx.y * QT;
    const int tid = threadIdx.x;
    const int lane = tid & 63;
    const int wave = tid >> 6;
    const size_t base = (size_t)bh * SEQ * D;

    // stage KVT (bf16 global, swizzle: 8-elem seg ^ (row&7))
    {
        const __bf16* kvg = KVT + (size_t)bh * D * D;
#pragma unroll
        for (int j = 0; j < 8; ++j) {
            const int f   = tid + 256 * j;
            const int e   = f >> 4;
            const int seg = f & 15;
            const bf16x8 v = *(const bf16x8*)(kvg + (size_t)f * 8);
            *(bf16x8*)(&sKVT[e][(seg ^ (e & 7)) * 8]) = v;
        }
    }
    if (tid < 16) {
        *(bf16x8*)(&sZ[tid * 8]) = *(const bf16x8*)(Zb + bh * D + tid * 8);
    }
    // stage phi(Q) as bf16, swizzled
    {
#pragma unroll
        for (int j = 0; j < 8; ++j) {
            const int f  = tid + 256 * j;
            const int r  = f >> 5;
            const int c4 = (f & 31) * 4;
            const float4 qv = *(const float4*)(Q + base + (size_t)(q0 + r) * D + c4);
            bf16x4 qb;
            qb[0] = (__bf16)phi1(qv.x); qb[1] = (__bf16)phi1(qv.y);
            qb[2] = (__bf16)phi1(qv.z); qb[3] = (__bf16)phi1(qv.w);
            *(bf16x4*)(&sQ[r][c4 ^ ((r & 7) * 8)]) = qb;
        }
    }
    __syncthreads();

    f32x4 acc[8];
#pragma unroll
    for (int et = 0; et < 8; ++et) acc[et] = (f32x4){0.f, 0.f, 0.f, 0.f};
    f32x4 accz = (f32x4){0.f, 0.f, 0.f, 0.f};

    const int qw   = wave * 16;
    const int lrow = lane & 15;
    const int lq   = lane >> 4;

#pragma unroll
    for (int dblk = 0; dblk < 4; ++dblk) {
        const int dbase = dblk * 32 + lq * 8;
        const int arow  = qw + lrow;
        const bf16x8 af = *(const bf16x8*)(&sQ[arow][dbase ^ ((arow & 7) * 8)]);
        const bf16x8 zf = *(const bf16x8*)(&sZ[dbase]);
        accz = __builtin_amdgcn_mfma_f32_16x16x32_bf16(af, zf, accz, 0, 0, 0);
#pragma unroll
        for (int et = 0; et < 8; ++et) {
            const int brow = et * 16 + lrow;
            const bf16x8 bfr = *(const bf16x8*)(&sKVT[brow][dbase ^ ((brow & 7) * 8)]);
            acc[et] = __builtin_amdgcn_mfma_f32_16x16x32_bf16(af, bfr, acc[et], 0, 0, 0);
        }
    }

    // epilogue: C/D layout col=lane&15, row=(lane>>4)*4+reg
    float inv[4];
#pragma unroll
    for (int r = 0; r < 4; ++r) inv[r] = 1.0f / (accz[r] + EPS);
    float* ob = out + base + (size_t)(q0 + qw + lq * 4) * D + lrow;
#pragma unroll
    for (int r = 0; r < 4; ++r) {
#pragma unroll
        for (int et = 0; et < 8; ++et) {
            ob[(size_t)r * D + et * 16] = acc[et][r] * inv[r];
        }
    }
}

extern "C" void kernel_launch(void* const* d_in, const int* in_sizes, int n_in,
                              void* d_out, int out_size, void* d_ws, size_t ws_size,
                              hipStream_t stream) {
    const float* Q = (const float*)d_in[0];
    const float* K = (const float*)d_in[1];
    const float* V = (const float*)d_in[2];
    float* out = (float*)d_out;

    // ws layout: [KVTp: P*NBH*D*D f32][Zp: P*NBH*D f32][KVT: NBH*D*D bf16][Zb: NBH*D bf16]
    const size_t per_split_f = (size_t)NBH * D * D + (size_t)NBH * D;
    const size_t bf16_bytes  = ((size_t)NBH * D * D + (size_t)NBH * D) * sizeof(__bf16);
    int P = 8;
    while (P > 1 && (size_t)P * per_split_f * sizeof(float) + bf16_bytes > ws_size) P >>= 1;
    const int chunk = SEQ / P;   // 512 at P=8; chunk/TK = 32 tiles (> prologue depth 3)

    float*  KVTp = (float*)d_ws;
    float*  Zp   = KVTp + (size_t)P * NBH * D * D;
    __bf16* KVT  = (__bf16*)(Zp + (size_t)P * NBH * D);
    __bf16* Zb   = KVT + (size_t)NBH * D * D;

    kv_partial_mfma<<<dim3(P, NBH), 512, 0, stream>>>(K, V, KVTp, Zp, chunk);

    constexpr int RED_ITEMS = NBH * D * D / 8 + NBH * D / 8;
    reduce_bf16_kernel<<<(RED_ITEMS + 255) / 256, 256, 0, stream>>>(KVTp, Zp, KVT, Zb, P);

    attn_out_mfma<<<dim3(NBH, SEQ / QT), 256, 0, stream>>>(Q, KVT, Zb, out);
}

// Round 18
// 119.115 us; speedup vs baseline: 1.6200x; 1.1351x over previous
//
#include <hip/hip_runtime.h>
#include <stdint.h>

#define EPS 1e-6f

constexpr int D    = 128;   // head_dim
constexpr int SEQ  = 4096;  // seq_len
constexpr int NBH  = 64;    // bsz*num_heads
constexpr int TK   = 16;    // k rows per LDS tile (pass 1)
constexpr int QT   = 64;    // q rows per block (pass 2)

typedef __attribute__((ext_vector_type(8)))  __bf16 bf16x8;
typedef __attribute__((ext_vector_type(4)))  __bf16 bf16x4;
typedef __attribute__((ext_vector_type(4)))  float  f32x4;
typedef __attribute__((ext_vector_type(16))) float  f32x16;

typedef const __attribute__((address_space(1))) uint32_t* as1_u32p;
typedef __attribute__((address_space(3))) uint32_t*       as3_u32p;

__device__ __forceinline__ float phi1(float x) {
    // elu(x)+1 : x>0 -> x+1 ; x<=0 -> exp(x). Branchless.
    return fmaxf(x, 0.0f) + __expf(fminf(x, 0.0f));
}

// ---------------- Pass 1 (MFMA + global_load_lds, depth-3 pipeline, NT loads):
// KVTp[split][bh][e][d] = sum_k V[k][e]*phiK[k][d]  (f32 partials)
// R18 change vs R17: aux=2 (CPol NT bit, gfx940+ encoding SC0=1/NT=2/SC1=16) on the
// K/V streaming loads. K+V = 268 MB > 256 MB L3 -> the pass thrashes Infinity Cache
// (R17: FETCH=131MB of 268MB demanded, effective service pinned ~2.6 TB/s across 11
// structural variants). NT marks the streams non-temporal to avoid L3 churn.
__global__ __launch_bounds__(512, 4) void kv_partial_mfma(const float* __restrict__ K,
                                                          const float* __restrict__ V,
                                                          float* __restrict__ KVTp,
                                                          float* __restrict__ Zp,
                                                          int chunk) {
    __shared__ float stile[4][2][TK][D];   // [buf][K|V][k][col] = 64 KB -> 2 blocks/CU

    const int split = blockIdx.x, bh = blockIdx.y;
    const int tid  = threadIdx.x;
    const int lane = tid & 63;
    const int wave = tid >> 6;
    const int k0   = split * chunk;
    const size_t base = (size_t)bh * SEQ * D;

    // staging role: waves 0-3 issue K tile, waves 4-7 issue V tile; 2 x 16B per thread
    const int  mat = wave >> 2;             // 0 = K, 1 = V
    const int  w4  = wave & 3;
    const float* __restrict__ src = mat ? V : K;
    const int eoff0 = (w4 * 2 + 0) * 256 + lane * 4;  // float offset within [16][128] tile
    const int eoff1 = (w4 * 2 + 1) * 256 + lane * 4;

    // compute role: 2e x 4d wave grid
    const int we = wave >> 2;                        // 0..1 -> e-base we*64
    const int wd = wave & 3;                         // 0..3 -> d-strip wd*32
    const int er0 = we * 64 + (lane & 31);           // A row (e), strip 0
    const int er1 = er0 + 32;                        // A row (e), strip 1
    const int dr  = wd * 32 + (lane & 31);           // B col (d)
    const int kh  = (lane >> 5) * 8;                 // k-half of the 16-k step

    f32x16 acc0, acc1;
#pragma unroll
    for (int i = 0; i < 16; ++i) { acc0[i] = 0.f; acc1[i] = 0.f; }
    float zacc = 0.f;
    const bool doZ = (we == 0);   // waves 0-3 own Z for their own d-strip

    const int tiles = chunk / TK;

#define ISSUE(BUF, T) { \
        const float* g = src + base + (size_t)(k0 + (T) * TK) * D; \
        float* l = &stile[BUF][mat][0][0]; \
        __builtin_amdgcn_global_load_lds((as1_u32p)(const void*)(g + eoff0), \
                                         (as3_u32p)(void*)(l + eoff0), 16, 0, 2); \
        __builtin_amdgcn_global_load_lds((as1_u32p)(const void*)(g + eoff1), \
                                         (as3_u32p)(void*)(l + eoff1), 16, 0, 2); }

    // prologue: 3 tiles in flight (6 loads/wave)
    ISSUE(0, 0)
    ISSUE(1, 1)
    ISSUE(2, 2)

    for (int t = 0; t < tiles; ++t) {
        const int buf = t & 3;
        if (t + 3 < tiles) {
            ISSUE((t + 3) & 3, t + 3)
            asm volatile("s_waitcnt vmcnt(6)" ::: "memory");  // t's 2 done; 6 in flight
        } else if (t + 2 < tiles) {
            asm volatile("s_waitcnt vmcnt(4)" ::: "memory");
        } else if (t + 1 < tiles) {
            asm volatile("s_waitcnt vmcnt(2)" ::: "memory");
        } else {
            asm volatile("s_waitcnt vmcnt(0)" ::: "memory");
        }
        __builtin_amdgcn_s_barrier();        // all waves' tile-t writes visible
        __builtin_amdgcn_sched_barrier(0);

        const float* kt = &stile[buf][0][0][0];
        const float* vt = &stile[buf][1][0][0];

        bf16x8 av0, av1, bk;
#pragma unroll
        for (int i = 0; i < 8; ++i) {
            const float fv0 = vt[(kh + i) * D + er0];
            const float fv1 = vt[(kh + i) * D + er1];
            const float p   = phi1(kt[(kh + i) * D + dr]);
            av0[i] = (__bf16)fv0;
            av1[i] = (__bf16)fv1;
            bk[i]  = (__bf16)p;
            if (doZ) zacc += p;
        }
        acc0 = __builtin_amdgcn_mfma_f32_32x32x16_bf16(av0, bk, acc0, 0, 0, 0);
        acc1 = __builtin_amdgcn_mfma_f32_32x32x16_bf16(av1, bk, acc1, 0, 0, 0);

        asm volatile("s_waitcnt lgkmcnt(0)" ::: "memory");   // my ds_reads retired
        __builtin_amdgcn_s_barrier();                         // buf reusable at t+1's ISSUE
        __builtin_amdgcn_sched_barrier(0);
    }
#undef ISSUE

    // store C partials (f32). C/D: col = lane&31, row = (reg&3) + 8*(reg>>2) + 4*(lane>>5)
    float* kvb = KVTp + ((size_t)split * NBH + bh) * D * D;
    const int ebase = we * 64 + 4 * (lane >> 5);
    const int dcol  = wd * 32 + (lane & 31);
#pragma unroll
    for (int r = 0; r < 16; ++r) {
        const int e = ebase + (r & 3) + 8 * (r >> 2);
        kvb[(size_t)e * D + dcol]        = acc0[r];
        kvb[(size_t)(e + 32) * D + dcol] = acc1[r];
    }

    // Z: lane l covers k-half kh at d = dr; lane l^32 covers the other k-half
    if (doZ) {
        zacc += __shfl_xor(zacc, 32);
        if (lane < 32) {
            Zp[((size_t)split * NBH + bh) * D + wd * 32 + lane] = zacc;
        }
    }
}

// ---------------- Reduce partials -> bf16: KVT[bh][e][d], Zb[bh][d]
__global__ __launch_bounds__(256) void reduce_bf16_kernel(const float* __restrict__ KVTp,
                                                          const float* __restrict__ Zp,
                                                          __bf16* __restrict__ KVT,
                                                          __bf16* __restrict__ Zb,
                                                          int P) {
    constexpr int KVF8 = NBH * D * D / 8;  // 131072
    constexpr int ZF8  = NBH * D / 8;      // 1024
    const int idx = blockIdx.x * 256 + threadIdx.x;
    if (idx < KVF8) {
        const size_t b0 = (size_t)idx * 8;
        float4 s0 = *(const float4*)(KVTp + b0);
        float4 s1 = *(const float4*)(KVTp + b0 + 4);
        for (int s = 1; s < P; ++s) {
            const float* p = KVTp + (size_t)s * NBH * D * D + b0;
            const float4 a = *(const float4*)(p);
            const float4 b = *(const float4*)(p + 4);
            s0.x += a.x; s0.y += a.y; s0.z += a.z; s0.w += a.w;
            s1.x += b.x; s1.y += b.y; s1.z += b.z; s1.w += b.w;
        }
        bf16x8 o;
        o[0] = (__bf16)s0.x; o[1] = (__bf16)s0.y; o[2] = (__bf16)s0.z; o[3] = (__bf16)s0.w;
        o[4] = (__bf16)s1.x; o[5] = (__bf16)s1.y; o[6] = (__bf16)s1.z; o[7] = (__bf16)s1.w;
        *(bf16x8*)(KVT + b0) = o;
    } else if (idx < KVF8 + ZF8) {
        const size_t b0 = (size_t)(idx - KVF8) * 8;
        float4 s0 = *(const float4*)(Zp + b0);
        float4 s1 = *(const float4*)(Zp + b0 + 4);
        for (int s = 1; s < P; ++s) {
            const float* p = Zp + (size_t)s * NBH * D + b0;
            const float4 a = *(const float4*)(p);
            const float4 b = *(const float4*)(p + 4);
            s0.x += a.x; s0.y += a.y; s0.z += a.z; s0.w += a.w;
            s1.x += b.x; s1.y += b.y; s1.z += b.z; s1.w += b.w;
        }
        bf16x8 o;
        o[0] = (__bf16)s0.x; o[1] = (__bf16)s0.y; o[2] = (__bf16)s0.z; o[3] = (__bf16)s0.w;
        o[4] = (__bf16)s1.x; o[5] = (__bf16)s1.y; o[6] = (__bf16)s1.z; o[7] = (__bf16)s1.w;
        *(bf16x8*)(Zb + b0) = o;
    }
}

// ---------------- Pass 2 (MFMA): out[q][e] = (phiQ[q][:] @ KV) / (phiQ[q][:] . Z + EPS)
__global__ __launch_bounds__(256, 3) void attn_out_mfma(const float* __restrict__ Q,
                                                        const __bf16* __restrict__ KVT,
                                                        const __bf16* __restrict__ Zb,
                                                        float* __restrict__ out) {
    __shared__ __bf16 sKVT[D][D];   // 32 KB, row-XOR-swizzled
    __shared__ __bf16 sQ[QT][D];    // 16 KB, row-XOR-swizzled
    __shared__ __bf16 sZ[D];        // 256 B, linear

    const int bh  = blockIdx.x;
    const int q0  = blockIdx.y * QT;
    const int tid = threadIdx.x;
    const int lane = tid & 63;
    const int wave = tid >> 6;
    const size_t base = (size_t)bh * SEQ * D;

    // stage KVT (bf16 global, swizzle: 8-elem seg ^ (row&7))
    {
        const __bf16* kvg = KVT + (size_t)bh * D * D;
#pragma unroll
        for (int j = 0; j < 8; ++j) {
            const int f   = tid + 256 * j;
            const int e   = f >> 4;
            const int seg = f & 15;
            const bf16x8 v = *(const bf16x8*)(kvg + (size_t)f * 8);
            *(bf16x8*)(&sKVT[e][(seg ^ (e & 7)) * 8]) = v;
        }
    }
    if (tid < 16) {
        *(bf16x8*)(&sZ[tid * 8]) = *(const bf16x8*)(Zb + bh * D + tid * 8);
    }
    // stage phi(Q) as bf16, swizzled
    {
#pragma unroll
        for (int j = 0; j < 8; ++j) {
            const int f  = tid + 256 * j;
            const int r  = f >> 5;
            const int c4 = (f & 31) * 4;
            const float4 qv = *(const float4*)(Q + base + (size_t)(q0 + r) * D + c4);
            bf16x4 qb;
            qb[0] = (__bf16)phi1(qv.x); qb[1] = (__bf16)phi1(qv.y);
            qb[2] = (__bf16)phi1(qv.z); qb[3] = (__bf16)phi1(qv.w);
            *(bf16x4*)(&sQ[r][c4 ^ ((r & 7) * 8)]) = qb;
        }
    }
    __syncthreads();

    f32x4 acc[8];
#pragma unroll
    for (int et = 0; et < 8; ++et) acc[et] = (f32x4){0.f, 0.f, 0.f, 0.f};
    f32x4 accz = (f32x4){0.f, 0.f, 0.f, 0.f};

    const int qw   = wave * 16;
    const int lrow = lane & 15;
    const int lq   = lane >> 4;

#pragma unroll
    for (int dblk = 0; dblk < 4; ++dblk) {
        const int dbase = dblk * 32 + lq * 8;
        const int arow  = qw + lrow;
        const bf16x8 af = *(const bf16x8*)(&sQ[arow][dbase ^ ((arow & 7) * 8)]);
        const bf16x8 zf = *(const bf16x8*)(&sZ[dbase]);
        accz = __builtin_amdgcn_mfma_f32_16x16x32_bf16(af, zf, accz, 0, 0, 0);
#pragma unroll
        for (int et = 0; et < 8; ++et) {
            const int brow = et * 16 + lrow;
            const bf16x8 bfr = *(const bf16x8*)(&sKVT[brow][dbase ^ ((brow & 7) * 8)]);
            acc[et] = __builtin_amdgcn_mfma_f32_16x16x32_bf16(af, bfr, acc[et], 0, 0, 0);
        }
    }

    // epilogue: C/D layout col=lane&15, row=(lane>>4)*4+reg
    float inv[4];
#pragma unroll
    for (int r = 0; r < 4; ++r) inv[r] = 1.0f / (accz[r] + EPS);
    float* ob = out + base + (size_t)(q0 + qw + lq * 4) * D + lrow;
#pragma unroll
    for (int r = 0; r < 4; ++r) {
#pragma unroll
        for (int et = 0; et < 8; ++et) {
            ob[(size_t)r * D + et * 16] = acc[et][r] * inv[r];
        }
    }
}

extern "C" void kernel_launch(void* const* d_in, const int* in_sizes, int n_in,
                              void* d_out, int out_size, void* d_ws, size_t ws_size,
                              hipStream_t stream) {
    const float* Q = (const float*)d_in[0];
    const float* K = (const float*)d_in[1];
    const float* V = (const float*)d_in[2];
    float* out = (float*)d_out;

    // ws layout: [KVTp: P*NBH*D*D f32][Zp: P*NBH*D f32][KVT: NBH*D*D bf16][Zb: NBH*D bf16]
    const size_t per_split_f = (size_t)NBH * D * D + (size_t)NBH * D;
    const size_t bf16_bytes  = ((size_t)NBH * D * D + (size_t)NBH * D) * sizeof(__bf16);
    int P = 8;
    while (P > 1 && (size_t)P * per_split_f * sizeof(float) + bf16_bytes > ws_size) P >>= 1;
    const int chunk = SEQ / P;   // 512 at P=8; chunk/TK = 32 tiles (> prologue depth 3)

    float*  KVTp = (float*)d_ws;
    float*  Zp   = KVTp + (size_t)P * NBH * D * D;
    __bf16* KVT  = (__bf16*)(Zp + (size_t)P * NBH * D);
    __bf16* Zb   = KVT + (size_t)NBH * D * D;

    kv_partial_mfma<<<dim3(P, NBH), 512, 0, stream>>>(K, V, KVTp, Zp, chunk);

    constexpr int RED_ITEMS = NBH * D * D / 8 + NBH * D / 8;
    reduce_bf16_kernel<<<(RED_ITEMS + 255) / 256, 256, 0, stream>>>(KVTp, Zp, KVT, Zb, P);

    attn_out_mfma<<<dim3(NBH, SEQ / QT), 256, 0, stream>>>(Q, KVT, Zb, out);
}

// Round 19
// 109.690 us; speedup vs baseline: 1.7592x; 1.0859x over previous
//
#include <hip/hip_runtime.h>
#include <stdint.h>

#define EPS 1e-6f

constexpr int D    = 128;   // head_dim
constexpr int SEQ  = 4096;  // seq_len
constexpr int NBH  = 64;    // bsz*num_heads
constexpr int TK   = 16;    // k rows per LDS tile (pass 1)
constexpr int QT   = 64;    // q rows per block (pass 2)

typedef __attribute__((ext_vector_type(8)))  __bf16 bf16x8;
typedef __attribute__((ext_vector_type(4)))  __bf16 bf16x4;
typedef __attribute__((ext_vector_type(4)))  float  f32x4;
typedef __attribute__((ext_vector_type(16))) float  f32x16;

typedef const __attribute__((address_space(1))) uint32_t* as1_u32p;
typedef __attribute__((address_space(3))) uint32_t*       as3_u32p;

__device__ __forceinline__ float phi1(float x) {
    // elu(x)+1 : x>0 -> x+1 ; x<=0 -> exp(x). Branchless.
    return fmaxf(x, 0.0f) + __expf(fminf(x, 0.0f));
}

// ---------------- Pass 1 (MFMA + global_load_lds, depth-3 pipeline, NT loads):
// KVTp[split][bh][e][d] = sum_k V[k][e]*phiK[k][d]  (f32 partials)
// aux=2 (CPol NT) on the K/V streams: K+V = 268 MB > 256 MB L3, so cacheable reads
// thrash Infinity Cache (R17: service pinned ~2.6 TB/s across 11 structural variants).
// NT bypass was the unlock: pass 1 103 -> <81 µs (R18).
__global__ __launch_bounds__(512, 4) void kv_partial_mfma(const float* __restrict__ K,
                                                          const float* __restrict__ V,
                                                          float* __restrict__ KVTp,
                                                          float* __restrict__ Zp,
                                                          int chunk) {
    __shared__ float stile[4][2][TK][D];   // [buf][K|V][k][col] = 64 KB -> 2 blocks/CU

    const int split = blockIdx.x, bh = blockIdx.y;
    const int tid  = threadIdx.x;
    const int lane = tid & 63;
    const int wave = tid >> 6;
    const int k0   = split * chunk;
    const size_t base = (size_t)bh * SEQ * D;

    // staging role: waves 0-3 issue K tile, waves 4-7 issue V tile; 2 x 16B per thread
    const int  mat = wave >> 2;             // 0 = K, 1 = V
    const int  w4  = wave & 3;
    const float* __restrict__ src = mat ? V : K;
    const int eoff0 = (w4 * 2 + 0) * 256 + lane * 4;  // float offset within [16][128] tile
    const int eoff1 = (w4 * 2 + 1) * 256 + lane * 4;

    // compute role: 2e x 4d wave grid
    const int we = wave >> 2;                        // 0..1 -> e-base we*64
    const int wd = wave & 3;                         // 0..3 -> d-strip wd*32
    const int er0 = we * 64 + (lane & 31);           // A row (e), strip 0
    const int er1 = er0 + 32;                        // A row (e), strip 1
    const int dr  = wd * 32 + (lane & 31);           // B col (d)
    const int kh  = (lane >> 5) * 8;                 // k-half of the 16-k step

    f32x16 acc0, acc1;
#pragma unroll
    for (int i = 0; i < 16; ++i) { acc0[i] = 0.f; acc1[i] = 0.f; }
    float zacc = 0.f;
    const bool doZ = (we == 0);   // waves 0-3 own Z for their own d-strip

    const int tiles = chunk / TK;

#define ISSUE(BUF, T) { \
        const float* g = src + base + (size_t)(k0 + (T) * TK) * D; \
        float* l = &stile[BUF][mat][0][0]; \
        __builtin_amdgcn_global_load_lds((as1_u32p)(const void*)(g + eoff0), \
                                         (as3_u32p)(void*)(l + eoff0), 16, 0, 2); \
        __builtin_amdgcn_global_load_lds((as1_u32p)(const void*)(g + eoff1), \
                                         (as3_u32p)(void*)(l + eoff1), 16, 0, 2); }

    // prologue: 3 tiles in flight (6 loads/wave)
    ISSUE(0, 0)
    ISSUE(1, 1)
    ISSUE(2, 2)

    for (int t = 0; t < tiles; ++t) {
        const int buf = t & 3;
        if (t + 3 < tiles) {
            ISSUE((t + 3) & 3, t + 3)
            asm volatile("s_waitcnt vmcnt(6)" ::: "memory");  // t's 2 done; 6 in flight
        } else if (t + 2 < tiles) {
            asm volatile("s_waitcnt vmcnt(4)" ::: "memory");
        } else if (t + 1 < tiles) {
            asm volatile("s_waitcnt vmcnt(2)" ::: "memory");
        } else {
            asm volatile("s_waitcnt vmcnt(0)" ::: "memory");
        }
        __builtin_amdgcn_s_barrier();        // all waves' tile-t writes visible
        __builtin_amdgcn_sched_barrier(0);

        const float* kt = &stile[buf][0][0][0];
        const float* vt = &stile[buf][1][0][0];

        bf16x8 av0, av1, bk;
#pragma unroll
        for (int i = 0; i < 8; ++i) {
            const float fv0 = vt[(kh + i) * D + er0];
            const float fv1 = vt[(kh + i) * D + er1];
            const float p   = phi1(kt[(kh + i) * D + dr]);
            av0[i] = (__bf16)fv0;
            av1[i] = (__bf16)fv1;
            bk[i]  = (__bf16)p;
            if (doZ) zacc += p;
        }
        acc0 = __builtin_amdgcn_mfma_f32_32x32x16_bf16(av0, bk, acc0, 0, 0, 0);
        acc1 = __builtin_amdgcn_mfma_f32_32x32x16_bf16(av1, bk, acc1, 0, 0, 0);

        asm volatile("s_waitcnt lgkmcnt(0)" ::: "memory");   // my ds_reads retired
        __builtin_amdgcn_s_barrier();                         // buf reusable at t+1's ISSUE
        __builtin_amdgcn_sched_barrier(0);
    }
#undef ISSUE

    // store C partials (f32). C/D: col = lane&31, row = (reg&3) + 8*(reg>>2) + 4*(lane>>5)
    float* kvb = KVTp + ((size_t)split * NBH + bh) * D * D;
    const int ebase = we * 64 + 4 * (lane >> 5);
    const int dcol  = wd * 32 + (lane & 31);
#pragma unroll
    for (int r = 0; r < 16; ++r) {
        const int e = ebase + (r & 3) + 8 * (r >> 2);
        kvb[(size_t)e * D + dcol]        = acc0[r];
        kvb[(size_t)(e + 32) * D + dcol] = acc1[r];
    }

    // Z: lane l covers k-half kh at d = dr; lane l^32 covers the other k-half
    if (doZ) {
        zacc += __shfl_xor(zacc, 32);
        if (lane < 32) {
            Zp[((size_t)split * NBH + bh) * D + wd * 32 + lane] = zacc;
        }
    }
}

// ---------------- Reduce partials -> bf16: KVT[bh][e][d], Zb[bh][d]
__global__ __launch_bounds__(256) void reduce_bf16_kernel(const float* __restrict__ KVTp,
                                                          const float* __restrict__ Zp,
                                                          __bf16* __restrict__ KVT,
                                                          __bf16* __restrict__ Zb,
                                                          int P) {
    constexpr int KVF8 = NBH * D * D / 8;  // 131072
    constexpr int ZF8  = NBH * D / 8;      // 1024
    const int idx = blockIdx.x * 256 + threadIdx.x;
    if (idx < KVF8) {
        const size_t b0 = (size_t)idx * 8;
        float4 s0 = *(const float4*)(KVTp + b0);
        float4 s1 = *(const float4*)(KVTp + b0 + 4);
        for (int s = 1; s < P; ++s) {
            const float* p = KVTp + (size_t)s * NBH * D * D + b0;
            const float4 a = *(const float4*)(p);
            const float4 b = *(const float4*)(p + 4);
            s0.x += a.x; s0.y += a.y; s0.z += a.z; s0.w += a.w;
            s1.x += b.x; s1.y += b.y; s1.z += b.z; s1.w += b.w;
        }
        bf16x8 o;
        o[0] = (__bf16)s0.x; o[1] = (__bf16)s0.y; o[2] = (__bf16)s0.z; o[3] = (__bf16)s0.w;
        o[4] = (__bf16)s1.x; o[5] = (__bf16)s1.y; o[6] = (__bf16)s1.z; o[7] = (__bf16)s1.w;
        *(bf16x8*)(KVT + b0) = o;
    } else if (idx < KVF8 + ZF8) {
        const size_t b0 = (size_t)(idx - KVF8) * 8;
        float4 s0 = *(const float4*)(Zp + b0);
        float4 s1 = *(const float4*)(Zp + b0 + 4);
        for (int s = 1; s < P; ++s) {
            const float* p = Zp + (size_t)s * NBH * D + b0;
            const float4 a = *(const float4*)(p);
            const float4 b = *(const float4*)(p + 4);
            s0.x += a.x; s0.y += a.y; s0.z += a.z; s0.w += a.w;
            s1.x += b.x; s1.y += b.y; s1.z += b.z; s1.w += b.w;
        }
        bf16x8 o;
        o[0] = (__bf16)s0.x; o[1] = (__bf16)s0.y; o[2] = (__bf16)s0.z; o[3] = (__bf16)s0.w;
        o[4] = (__bf16)s1.x; o[5] = (__bf16)s1.y; o[6] = (__bf16)s1.z; o[7] = (__bf16)s1.w;
        *(bf16x8*)(Zb + b0) = o;
    }
}

// ---------------- Pass 2 (MFMA): out[q][e] = (phiQ[q][:] @ KV) / (phiQ[q][:] . Z + EPS)
// NT stores on `out` (write-once, never re-read) keep it out of L3, so Q (134 MB)
// stays L3-resident across graph replays (Q + KVT + partials ~170 MB < 256 MB).
__global__ __launch_bounds__(256, 3) void attn_out_mfma(const float* __restrict__ Q,
                                                        const __bf16* __restrict__ KVT,
                                                        const __bf16* __restrict__ Zb,
                                                        float* __restrict__ out) {
    __shared__ __bf16 sKVT[D][D];   // 32 KB, row-XOR-swizzled
    __shared__ __bf16 sQ[QT][D];    // 16 KB, row-XOR-swizzled
    __shared__ __bf16 sZ[D];        // 256 B, linear

    const int bh  = blockIdx.x;
    const int q0  = blockIdx.y * QT;
    const int tid = threadIdx.x;
    const int lane = tid & 63;
    const int wave = tid >> 6;
    const size_t base = (size_t)bh * SEQ * D;

    // stage KVT (bf16 global, swizzle: 8-elem seg ^ (row&7))
    {
        const __bf16* kvg = KVT + (size_t)bh * D * D;
#pragma unroll
        for (int j = 0; j < 8; ++j) {
            const int f   = tid + 256 * j;
            const int e   = f >> 4;
            const int seg = f & 15;
            const bf16x8 v = *(const bf16x8*)(kvg + (size_t)f * 8);
            *(bf16x8*)(&sKVT[e][(seg ^ (e & 7)) * 8]) = v;
        }
    }
    if (tid < 16) {
        *(bf16x8*)(&sZ[tid * 8]) = *(const bf16x8*)(Zb + bh * D + tid * 8);
    }
    // stage phi(Q) as bf16, swizzled
    {
#pragma unroll
        for (int j = 0; j < 8; ++j) {
            const int f  = tid + 256 * j;
            const int r  = f >> 5;
            const int c4 = (f & 31) * 4;
            const float4 qv = *(const float4*)(Q + base + (size_t)(q0 + r) * D + c4);
            bf16x4 qb;
            qb[0] = (__bf16)phi1(qv.x); qb[1] = (__bf16)phi1(qv.y);
            qb[2] = (__bf16)phi1(qv.z); qb[3] = (__bf16)phi1(qv.w);
            *(bf16x4*)(&sQ[r][c4 ^ ((r & 7) * 8)]) = qb;
        }
    }
    __syncthreads();

    f32x4 acc[8];
#pragma unroll
    for (int et = 0; et < 8; ++et) acc[et] = (f32x4){0.f, 0.f, 0.f, 0.f};
    f32x4 accz = (f32x4){0.f, 0.f, 0.f, 0.f};

    const int qw   = wave * 16;
    const int lrow = lane & 15;
    const int lq   = lane >> 4;

#pragma unroll
    for (int dblk = 0; dblk < 4; ++dblk) {
        const int dbase = dblk * 32 + lq * 8;
        const int arow  = qw + lrow;
        const bf16x8 af = *(const bf16x8*)(&sQ[arow][dbase ^ ((arow & 7) * 8)]);
        const bf16x8 zf = *(const bf16x8*)(&sZ[dbase]);
        accz = __builtin_amdgcn_mfma_f32_16x16x32_bf16(af, zf, accz, 0, 0, 0);
#pragma unroll
        for (int et = 0; et < 8; ++et) {
            const int brow = et * 16 + lrow;
            const bf16x8 bfr = *(const bf16x8*)(&sKVT[brow][dbase ^ ((brow & 7) * 8)]);
            acc[et] = __builtin_amdgcn_mfma_f32_16x16x32_bf16(af, bfr, acc[et], 0, 0, 0);
        }
    }

    // epilogue: C/D layout col=lane&15, row=(lane>>4)*4+reg; NT stores (no L3 alloc)
    float inv[4];
#pragma unroll
    for (int r = 0; r < 4; ++r) inv[r] = 1.0f / (accz[r] + EPS);
    float* ob = out + base + (size_t)(q0 + qw + lq * 4) * D + lrow;
#pragma unroll
    for (int r = 0; r < 4; ++r) {
#pragma unroll
        for (int et = 0; et < 8; ++et) {
            __builtin_nontemporal_store(acc[et][r] * inv[r], &ob[(size_t)r * D + et * 16]);
        }
    }
}

extern "C" void kernel_launch(void* const* d_in, const int* in_sizes, int n_in,
                              void* d_out, int out_size, void* d_ws, size_t ws_size,
                              hipStream_t stream) {
    const float* Q = (const float*)d_in[0];
    const float* K = (const float*)d_in[1];
    const float* V = (const float*)d_in[2];
    float* out = (float*)d_out;

    // ws layout: [KVTp: P*NBH*D*D f32][Zp: P*NBH*D f32][KVT: NBH*D*D bf16][Zb: NBH*D bf16]
    const size_t per_split_f = (size_t)NBH * D * D + (size_t)NBH * D;
    const size_t bf16_bytes  = ((size_t)NBH * D * D + (size_t)NBH * D) * sizeof(__bf16);
    int P = 8;
    while (P > 1 && (size_t)P * per_split_f * sizeof(float) + bf16_bytes > ws_size) P >>= 1;
    const int chunk = SEQ / P;   // 512 at P=8; chunk/TK = 32 tiles (> prologue depth 3)

    float*  KVTp = (float*)d_ws;
    float*  Zp   = KVTp + (size_t)P * NBH * D * D;
    __bf16* KVT  = (__bf16*)(Zp + (size_t)P * NBH * D);
    __bf16* Zb   = KVT + (size_t)NBH * D * D;

    kv_partial_mfma<<<dim3(P, NBH), 512, 0, stream>>>(K, V, KVTp, Zp, chunk);

    constexpr int RED_ITEMS = NBH * D * D / 8 + NBH * D / 8;
    reduce_bf16_kernel<<<(RED_ITEMS + 255) / 256, 256, 0, stream>>>(KVTp, Zp, KVT, Zb, P);

    attn_out_mfma<<<dim3(NBH, SEQ / QT), 256, 0, stream>>>(Q, KVT, Zb, out);
}